// Round 6
// baseline (86.246 us; speedup 1.0000x reference)
//
#include <hip/hip_runtime.h>

// Problem constants (fixed by setup_inputs): B=8, N=128, C=64, S=64, basis=20
constexpr int N = 128, S = 64;
constexpr float INV_AVG = 1.0f / 49.0f;   // AVG_NOBJ
constexpr float SLOPE = 0.01f;            // leaky_relu neg slope

// Native 4-float vector for nontemporal stores.
typedef float f4 __attribute__((ext_vector_type(4)));

// xs swizzle: element (row r, d) lives at float4-slot r*16 + ((d>>2 + r)&15).
// Rotating the d-quads by the row index makes the 4 j-rows a P4 wave touches
// per ds_read_b128 land in disjoint bank groups (conflict-free), while P1
// stays a permutation (2-way, free) and P2 stays wave-uniform broadcast.
__device__ __forceinline__ int xs_q(int r, int qd) {        // float4 index
  return r * 16 + ((qd + r) & 15);
}
__device__ __forceinline__ int xs_e(int r, int d) {         // float index
  return r * 64 + 4 * (((d >> 2) + r) & 15) + (d & 3);
}

// ---------------------------------------------------------------------------
// Single fused kernel, grid = 256 (one block per CU), block = (n, 4 i-rows).
//   out[n,i,j,s] = leaky( Cc[n,i,s] + R[n,j,s] + E[n,s] + bias[s]
//                         + delta_ij * (A[n,i,s] + D[n,s]) ) * mask[n,i,j]
//   A = x·W1, R = x·W2, Cc = x·W3  (Wk[d,s] = sum_a coefs[d,s,5a+k])
//   D/E[n,s] = sum_d sum_a agg_a[n,d] * coefs[d,s,5a+{3,4}]
// ---------------------------------------------------------------------------
__global__ __launch_bounds__(256) void fused_kernel(
    const float* __restrict__ x,      // [8][128][64]
    const float* __restrict__ mask,   // [8][128][128][1]
    const float* __restrict__ nobj,   // [8]
    const float* __restrict__ coefs,  // [64][64][20]
    const float* __restrict__ bias,   // [64]
    float* __restrict__ out)          // [8][128][128][64]
{
  __shared__ float xs[8192];     // x[n]  [i][d], quad-rotated (see xs_q)
  __shared__ float w2[4096];     // W2    [d][s]
  __shared__ float ag[256];      // [4][64] {sum/49, sum/nobj, max, min}
  __shared__ float part[2560];   // [10][4][64] cross-wave partials
  __shared__ float fin[512];     // base[4][64] then diag[4][64]

  const int tid = threadIdx.x;
  const int n   = blockIdx.x >> 5;
  const int i0  = (blockIdx.x & 31) << 2;   // this block's 4 i-rows

  // ---- P0: stage x[n] (32 KB, coalesced float4 reads, swizzled LDS write) --
  {
    const float4* xg = (const float4*)(x + n * N * 64);
    float4* xs4 = (float4*)xs;
#pragma unroll
    for (int k = 0; k < 8; ++k) {
      const int g = tid + k * 256;         // global float4 index
      const int r = g >> 4, q = g & 15;
      xs4[xs_q(r, q)] = xg[g];
    }
  }
  __syncthreads();

  // ---- P1: aggregations over i (sum/max/min) ----
  {
    const int d = tid & 63, grp = tid >> 6;
    float sm = 0.f, mx = -INFINITY, mn = INFINITY;
    for (int i = grp * 32; i < grp * 32 + 32; ++i) {
      float v = xs[xs_e(i, d)];            // permutation: 2-way bank (free)
      sm += v; mx = fmaxf(mx, v); mn = fminf(mn, v);
    }
    part[grp * 64 + d]       = sm;
    part[256 + grp * 64 + d] = mx;
    part[512 + grp * 64 + d] = mn;
  }
  __syncthreads();
  if (tid < 64) {
    float s0 = part[tid] + part[64 + tid] + part[128 + tid] + part[192 + tid];
    float m0 = fmaxf(fmaxf(part[256 + tid], part[320 + tid]),
                     fmaxf(part[384 + tid], part[448 + tid]));
    float n0 = fminf(fminf(part[512 + tid], part[576 + tid]),
                     fminf(part[640 + tid], part[704 + tid]));
    ag[tid]       = s0 * INV_AVG;   // 'sum'
    ag[64 + tid]  = s0 / nobj[n];   // 'mean'
    ag[128 + tid] = m0;             // 'max'
    ag[192 + tid] = n0;             // 'min'
  }
  __syncthreads();

  // ---- P2: one coefs pass: build W2 in LDS, accumulate A/Cc (4 i's)
  //          and D/E partials inline. Thread covers s=tid&63, d=k*4+(tid>>6).
  {
    const int g = tid >> 6;
    const int s = tid & 63;
    float pA[4] = {0,0,0,0}, pC[4] = {0,0,0,0};
    float pD = 0.f, pE = 0.f;
#pragma unroll
    for (int k = 0; k < 16; ++k) {
      const int e = k * 256 + tid;               // e = d*64 + s
      const int d = e >> 6;                      // wave-uniform
      const float4* cp = (const float4*)(coefs + e * 20);  // 80B rows
      float4 f0 = cp[0], f1 = cp[1], f2 = cp[2], f3 = cp[3], f4v = cp[4];
      float w1v = f0.x + f1.y + f2.z + f3.w;     // b = 0,5,10,15
      float w2v = f0.y + f1.z + f2.w + f4v.x;    // b = 1,6,11,16
      float w3v = f0.z + f1.w + f3.x + f4v.y;    // b = 2,7,12,17
      w2[e] = w2v;
#pragma unroll
      for (int m = 0; m < 4; ++m) {
        float xv = xs[xs_e(i0 + m, d)];          // wave-uniform broadcast
        pA[m] += xv * w1v;
        pC[m] += xv * w3v;
      }
      // D: cols 3,8,13,18 ; E: cols 4,9,14,19
      pD += ag[d] * f0.w + ag[64 + d] * f2.x + ag[128 + d] * f3.y + ag[192 + d] * f4v.z;
      pE += ag[d] * f1.x + ag[64 + d] * f2.y + ag[128 + d] * f3.z + ag[192 + d] * f4v.w;
    }
#pragma unroll
    for (int m = 0; m < 4; ++m) {
      part[m * 256 + g * 64 + s]       = pA[m];
      part[(4 + m) * 256 + g * 64 + s] = pC[m];
    }
    part[2048 + g * 64 + s] = pD;
    part[2304 + g * 64 + s] = pE;
  }
  __syncthreads();
  if (tid < 64) {
    const int s = tid;
    float D = part[2048 + s] + part[2048 + 64 + s] + part[2048 + 128 + s] + part[2048 + 192 + s];
    float E = part[2304 + s] + part[2304 + 64 + s] + part[2304 + 128 + s] + part[2304 + 192 + s];
    float bv = bias[s];
#pragma unroll
    for (int m = 0; m < 4; ++m) {
      float A = part[m * 256 + s] + part[m * 256 + 64 + s]
              + part[m * 256 + 128 + s] + part[m * 256 + 192 + s];
      float C = part[(4 + m) * 256 + s] + part[(4 + m) * 256 + 64 + s]
              + part[(4 + m) * 256 + 128 + s] + part[(4 + m) * 256 + 192 + s];
      fin[m * 64 + s]       = C + E + bv;   // j-invariant base
      fin[256 + m * 64 + s] = A + D;        // diagonal extra
    }
  }
  __syncthreads();

  // ---- P4: fused R-GEMM + assembly, all-b128 LDS reads.
  // Thread: l = s-quad (0..15), jb = j offset (0..3), wave w covers
  // j in [32w, 32w+32): j = 32w + 4t + jb  -> each store instruction writes
  // 4 consecutive j x 16 s-quads = 1 KB contiguous per wave.
  const int w  = tid >> 6;
  const int jb = (tid >> 4) & 3;
  const int l  = tid & 15;

  float4 base[4], diag[4];
#pragma unroll
  for (int m = 0; m < 4; ++m) {
    base[m] = *(const float4*)&fin[m * 64 + l * 4];
    diag[m] = *(const float4*)&fin[256 + m * 64 + l * 4];
  }

  float4 racc[8];
#pragma unroll
  for (int t = 0; t < 8; ++t) { racc[t].x = racc[t].y = racc[t].z = racc[t].w = 0.f; }

#pragma unroll 4
  for (int qd = 0; qd < 16; ++qd) {       // d-quad
    float4 wq0 = *(const float4*)&w2[(4 * qd + 0) * 64 + l * 4];  // 2-way (free)
    float4 wq1 = *(const float4*)&w2[(4 * qd + 1) * 64 + l * 4];
    float4 wq2 = *(const float4*)&w2[(4 * qd + 2) * 64 + l * 4];
    float4 wq3 = *(const float4*)&w2[(4 * qd + 3) * 64 + l * 4];
#pragma unroll
    for (int t = 0; t < 8; ++t) {
      const int j = w * 32 + 4 * t + jb;
      float4 xv = *(const float4*)&xs[4 * xs_q(j, qd)];  // conflict-free
      racc[t].x += xv.x * wq0.x + xv.y * wq1.x + xv.z * wq2.x + xv.w * wq3.x;
      racc[t].y += xv.x * wq0.y + xv.y * wq1.y + xv.z * wq2.y + xv.w * wq3.y;
      racc[t].z += xv.x * wq0.z + xv.y * wq1.z + xv.z * wq2.z + xv.w * wq3.z;
      racc[t].w += xv.x * wq0.w + xv.y * wq1.w + xv.z * wq2.w + xv.w * wq3.w;
    }
  }

  f4* out4 = (f4*)out;
#pragma unroll
  for (int t = 0; t < 8; ++t) {
    const int j = w * 32 + 4 * t + jb;
#pragma unroll
    for (int m = 0; m < 4; ++m) {
      const int i = i0 + m;
      float v0 = base[m].x + racc[t].x;
      float v1 = base[m].y + racc[t].y;
      float v2 = base[m].z + racc[t].z;
      float v3 = base[m].w + racc[t].w;
      if (j == i) {
        v0 += diag[m].x; v1 += diag[m].y;
        v2 += diag[m].z; v3 += diag[m].w;
      }
      v0 = (v0 >= 0.f) ? v0 : SLOPE * v0;
      v1 = (v1 >= 0.f) ? v1 : SLOPE * v1;
      v2 = (v2 >= 0.f) ? v2 : SLOPE * v2;
      v3 = (v3 >= 0.f) ? v3 : SLOPE * v3;
      float mk = mask[(n * N + i) * N + j];
      f4 o;
      o.x = v0 * mk; o.y = v1 * mk; o.z = v2 * mk; o.w = v3 * mk;
      __builtin_nontemporal_store(o, &out4[(size_t)((n * N + i) * N + j) * 16 + l]);
    }
  }
}

extern "C" void kernel_launch(void* const* d_in, const int* in_sizes, int n_in,
                              void* d_out, int out_size, void* d_ws, size_t ws_size,
                              hipStream_t stream) {
  const float* x     = (const float*)d_in[0];   // [8][128][64]
  const float* mask  = (const float*)d_in[1];   // [8][128][128][1]
  const float* nobj  = (const float*)d_in[2];   // [8]
  const float* coefs = (const float*)d_in[3];   // [64][64][20]
  const float* bias  = (const float*)d_in[4];   // [64]
  float* out = (float*)d_out;                   // [8][128][128][64]

  // 256 blocks = 8 n x 32 i-chunks of 4; one block per CU.
  fused_kernel<<<256, 256, 0, stream>>>(x, mask, nobj, coefs, bias, out);
}

// Round 7
// 81.385 us; speedup vs baseline: 1.0597x; 1.0597x over previous
//
#include <hip/hip_runtime.h>

// Problem constants (fixed by setup_inputs): B=8, N=128, C=64, S=64, basis=20
constexpr int N = 128, S = 64;
constexpr float INV_AVG = 1.0f / 49.0f;   // AVG_NOBJ
constexpr float SLOPE = 0.01f;            // leaky_relu neg slope

// Workspace layout (float offsets) — only 2.3 MB used
constexpr int WS_BASE = 0;        // [8][128][64]  Cc + E + bias  (j-invariant)
constexpr int WS_DIAG = 65536;    // [8][128][64]  A + D          (diagonal)
constexpr int WS_R    = 131072;   // [8][128][64]  x·W2           (row term)

// ---------------------------------------------------------------------------
// Kernel 1 (grid 256): block = (n, 4 i-rows). Small LDS (~12.5 KB) so other
// blocks can co-reside. Computes per-row A,R,Cc via one streamed coefs pass
// (redundant per block but L2-hot), redundant agg/D/E per block (cheap),
// writes pre-folded base/diag/R -- assemble then needs only 2 loads/output.
//   out[n,i,j,s] = leaky( base[n,i,s] + R[n,j,s] + delta_ij*diag[n,i,s] ) * mask
// ---------------------------------------------------------------------------
__global__ __launch_bounds__(256) void prep_kernel(
    const float* __restrict__ x,      // [8][128][64]
    const float* __restrict__ nobj,   // [8]
    const float* __restrict__ coefs,  // [64][64][20]
    const float* __restrict__ bias,   // [64]
    float* __restrict__ ws)
{
  __shared__ float xs[8192];     // x[n] [i][d]
  __shared__ float ag[256];      // [4][64] {sum/49, sum/nobj, max, min}
  __shared__ float part[3584];   // P1: 3x256 partials; P2: 14x256 partials

  const int tid = threadIdx.x;
  const int n   = blockIdx.x >> 5;
  const int i0  = (blockIdx.x & 31) << 2;

  // ---- P0: stage x[n] (32 KB, coalesced float4) ----
  {
    const float4* xg = (const float4*)(x + n * N * 64);
    float4* xs4 = (float4*)xs;
#pragma unroll
    for (int k = 0; k < 8; ++k) xs4[tid + k * 256] = xg[tid + k * 256];
  }
  __syncthreads();

  // ---- P1: aggregations over i (sum/max/min) ----
  {
    const int d = tid & 63, grp = tid >> 6;
    float sm = 0.f, mx = -INFINITY, mn = INFINITY;
    for (int i = grp * 32; i < grp * 32 + 32; ++i) {
      float v = xs[i * 64 + d];          // 2-way bank (free)
      sm += v; mx = fmaxf(mx, v); mn = fminf(mn, v);
    }
    part[grp * 64 + d]       = sm;
    part[256 + grp * 64 + d] = mx;
    part[512 + grp * 64 + d] = mn;
  }
  __syncthreads();
  if (tid < 64) {
    float s0 = part[tid] + part[64 + tid] + part[128 + tid] + part[192 + tid];
    float m0 = fmaxf(fmaxf(part[256 + tid], part[320 + tid]),
                     fmaxf(part[384 + tid], part[448 + tid]));
    float n0 = fminf(fminf(part[512 + tid], part[576 + tid]),
                     fminf(part[640 + tid], part[704 + tid]));
    ag[tid]       = s0 * INV_AVG;   // 'sum'
    ag[64 + tid]  = s0 / nobj[n];   // 'mean'
    ag[128 + tid] = m0;             // 'max'
    ag[192 + tid] = n0;             // 'min'
  }
  __syncthreads();

  // ---- P2: one coefs pass. Thread covers s=tid&63, d = k*4+(tid>>6).
  // Accumulates A/R/Cc for the block's 4 rows + D/E partials.
  {
    const int g = tid >> 6;
    const int s = tid & 63;
    float pA[4] = {0,0,0,0}, pR[4] = {0,0,0,0}, pC[4] = {0,0,0,0};
    float pD = 0.f, pE = 0.f;
#pragma unroll
    for (int k = 0; k < 16; ++k) {
      const int e = k * 256 + tid;               // e = d*64 + s
      const int d = e >> 6;                      // wave-uniform
      const float4* cp = (const float4*)(coefs + e * 20);  // 80B rows
      float4 f0 = cp[0], f1 = cp[1], f2 = cp[2], f3 = cp[3], f4v = cp[4];
      float w1v = f0.x + f1.y + f2.z + f3.w;     // b = 0,5,10,15
      float w2v = f0.y + f1.z + f2.w + f4v.x;    // b = 1,6,11,16
      float w3v = f0.z + f1.w + f3.x + f4v.y;    // b = 2,7,12,17
#pragma unroll
      for (int m = 0; m < 4; ++m) {
        float xv = xs[(i0 + m) * 64 + d];        // wave-uniform broadcast
        pA[m] += xv * w1v;
        pR[m] += xv * w2v;
        pC[m] += xv * w3v;
      }
      // D: cols 3,8,13,18 ; E: cols 4,9,14,19
      pD += ag[d] * f0.w + ag[64 + d] * f2.x + ag[128 + d] * f3.y + ag[192 + d] * f4v.z;
      pE += ag[d] * f1.x + ag[64 + d] * f2.y + ag[128 + d] * f3.z + ag[192 + d] * f4v.w;
    }
#pragma unroll
    for (int m = 0; m < 4; ++m) {
      part[m * 256 + g * 64 + s]        = pA[m];
      part[(4 + m) * 256 + g * 64 + s]  = pC[m];
      part[(8 + m) * 256 + g * 64 + s]  = pR[m];
    }
    part[3072 + g * 64 + s] = pD;
    part[3328 + g * 64 + s] = pE;
  }
  __syncthreads();

  // ---- P3: reduce + fold + write (64 threads, 256 B coalesced stores) ----
  if (tid < 64) {
    const int s = tid;
    float D = part[3072 + s] + part[3072 + 64 + s]
            + part[3072 + 128 + s] + part[3072 + 192 + s];
    float E = part[3328 + s] + part[3328 + 64 + s]
            + part[3328 + 128 + s] + part[3328 + 192 + s];
    float bv = bias[s];
#pragma unroll
    for (int m = 0; m < 4; ++m) {
      float A = part[m * 256 + s] + part[m * 256 + 64 + s]
              + part[m * 256 + 128 + s] + part[m * 256 + 192 + s];
      float C = part[(4 + m) * 256 + s] + part[(4 + m) * 256 + 64 + s]
              + part[(4 + m) * 256 + 128 + s] + part[(4 + m) * 256 + 192 + s];
      float R = part[(8 + m) * 256 + s] + part[(8 + m) * 256 + 64 + s]
              + part[(8 + m) * 256 + 128 + s] + part[(8 + m) * 256 + 192 + s];
      const int o = (n * N + i0 + m) * 64 + s;
      ws[WS_BASE + o] = C + E + bv;
      ws[WS_DIAG + o] = A + D;
      ws[WS_R    + o] = R;
    }
  }
}

// ---------------------------------------------------------------------------
// Kernel 2 (grid 8192, 32 blocks/CU): 1 float4 out per thread.
// 2 L2-hot loads + mask + rare diag; plain coalesced float4 store.
// Tiny VGPR footprint -> deep occupancy -> latency fully hidden; should run
// at the HBM write ceiling like the harness fill kernel does.
// ---------------------------------------------------------------------------
__global__ __launch_bounds__(256) void assemble_kernel(
    const float* __restrict__ ws,
    const float* __restrict__ mask,   // [8][128][128][1]
    float* __restrict__ out)          // [8][128][128][64]
{
  const int g  = blockIdx.x * 256 + threadIdx.x;  // float4 index
  const int l  = g & 15;
  const int p  = g >> 4;         // (n*128+i)*128 + j
  const int j  = p & 127;
  const int bi = p >> 7;         // n*128 + i
  const int i  = bi & 127;
  const int n  = bi >> 7;

  const float4* B4 = (const float4*)(ws + WS_BASE);
  const float4* G4 = (const float4*)(ws + WS_DIAG);
  const float4* R4 = (const float4*)(ws + WS_R);

  float4 b = B4[bi * 16 + l];
  float4 r = R4[(n * N + j) * 16 + l];
  float mk = mask[p];

  float v0 = b.x + r.x;
  float v1 = b.y + r.y;
  float v2 = b.z + r.z;
  float v3 = b.w + r.w;
  if (i == j) {
    float4 dg = G4[bi * 16 + l];
    v0 += dg.x; v1 += dg.y; v2 += dg.z; v3 += dg.w;
  }
  v0 = (v0 >= 0.f) ? v0 : SLOPE * v0;
  v1 = (v1 >= 0.f) ? v1 : SLOPE * v1;
  v2 = (v2 >= 0.f) ? v2 : SLOPE * v2;
  v3 = (v3 >= 0.f) ? v3 : SLOPE * v3;

  float4 o;
  o.x = v0 * mk; o.y = v1 * mk; o.z = v2 * mk; o.w = v3 * mk;
  ((float4*)out)[g] = o;
}

extern "C" void kernel_launch(void* const* d_in, const int* in_sizes, int n_in,
                              void* d_out, int out_size, void* d_ws, size_t ws_size,
                              hipStream_t stream) {
  const float* x     = (const float*)d_in[0];   // [8][128][64]
  const float* mask  = (const float*)d_in[1];   // [8][128][128][1]
  const float* nobj  = (const float*)d_in[2];   // [8]
  const float* coefs = (const float*)d_in[3];   // [64][64][20]
  const float* bias  = (const float*)d_in[4];   // [64]
  float* out = (float*)d_out;                   // [8][128][128][64]
  float* ws  = (float*)d_ws;                    // 196608 floats (~786 KB)

  prep_kernel<<<256, 256, 0, stream>>>(x, nobj, coefs, bias, ws);
  assemble_kernel<<<8192, 256, 0, stream>>>(ws, mask, out);
}